// Round 9
// baseline (173.261 us; speedup 1.0000x reference)
//
#include <hip/hip_runtime.h>
#include <hip/hip_bf16.h>

#define B_ 4
#define S_ 2048
#define H_ 8
#define E_ 64
#define NW 4      // waves per attention block
#define QB 16     // q rows per wave
#define KT 64     // k/v tile size
#define NT (S_ / KT)
#define HSPLIT 4  // proj: head-groups per s-tile (2 heads per block)

typedef __attribute__((ext_vector_type(8))) short bf16x8v;
typedef __attribute__((ext_vector_type(4))) float f32x4v;

static __device__ __forceinline__ unsigned short f2bf(float f) {
    __hip_bfloat16 h = __float2bfloat16(f);
    return *reinterpret_cast<unsigned short*>(&h);
}

// async global->LDS DMA, 16B/lane
static __device__ __forceinline__ void gl_lds16(const void* g, void* lds) {
    __builtin_amdgcn_global_load_lds(
        (const __attribute__((address_space(1))) unsigned int*)g,
        (__attribute__((address_space(3))) unsigned int*)lds, 16, 0, 0);
}

// ---------------------------------------------------------------------------
// Projection v2: high-occupancy, vector stores.
//   q = (x@Wq + bq) * 0.125*log2e -> bf16 [B,H,S,E]   (exp2 domain)
//   k = (x@Wk + bk)               -> bf16 [B,H,S,E]
//   v = (x@Wv + bv)               -> bf16 [B,H,E,S]   (pre-transposed)
// Q/K use SWAPPED mfma operands (D row=f, col=s) so each lane holds 4
// consecutive f values -> ushort4 stores. V keeps (D row=s, col=f): in the
// transposed output a lane's 4 consecutive s-rows are contiguous -> ushort4.
// grid = B * S/16 * HSPLIT, block = 192 (wave 0: Q, 1: K, 2: V)
// ---------------------------------------------------------------------------
__global__ __launch_bounds__(192)
void proj_kernel(const float* __restrict__ query, const float* __restrict__ key,
                 const float* __restrict__ value,
                 const float* __restrict__ Wq, const float* __restrict__ bq,
                 const float* __restrict__ Wk, const float* __restrict__ bk,
                 const float* __restrict__ Wv, const float* __restrict__ bv,
                 __hip_bfloat16* __restrict__ qp, __hip_bfloat16* __restrict__ kp,
                 __hip_bfloat16* __restrict__ vtp)
{
    const int tid  = threadIdx.x;
    const int wave = tid >> 6;
    const int lane = tid & 63;
    const int lr   = lane & 15;
    const int lh   = lane >> 4;
    const int ntile = S_ / 16;
    const int hb    = blockIdx.x % HSPLIT;                  // head group
    const int sbase = ((blockIdx.x / HSPLIT) % ntile) * 16;
    const int b     = blockIdx.x / (ntile * HSPLIT);

    const float* x    = (wave == 0) ? query : (wave == 1) ? key : value;
    const float* W    = (wave == 0) ? Wq    : (wave == 1) ? Wk  : Wv;
    const float* bias = (wave == 0) ? bq    : (wave == 1) ? bk  : bv;

    // W fragments: lane holds W[e = lh*8+j + 32*hf][f = cb*16+lr]
    bf16x8v wf[4][2];
#pragma unroll
    for (int cb = 0; cb < 4; ++cb)
#pragma unroll
        for (int hf = 0; hf < 2; ++hf)
#pragma unroll
            for (int j = 0; j < 8; ++j) {
                int e = lh * 8 + j + 32 * hf;
                wf[cb][hf][j] = (short)f2bf(W[e * E_ + cb * 16 + lr]);
            }

    // biases: swapped path (Q/K) indexed by f = cb*16 + 4*lh + r;
    //         V path indexed by f = cb*16 + lr
    float4 bias4[4];
    float  bvals[4];
#pragma unroll
    for (int cb = 0; cb < 4; ++cb) {
        bias4[cb] = *reinterpret_cast<const float4*>(bias + cb * 16 + 4 * lh);
        bvals[cb] = bias[cb * 16 + lr];
    }

    // 0.125 (1/sqrt E) * log2(e): attn softmax runs in exp2 domain
    const float QSCALE = 0.18033688011112042f;

#pragma unroll
    for (int hi = 0; hi < H_ / HSPLIT; ++hi) {
        const int h = hb * (H_ / HSPLIT) + hi;
        const float* xrow = x + (((size_t)b * S_ + sbase + lr) * H_ + h) * E_;
        const float4* xr = reinterpret_cast<const float4*>(xrow);
        float4 a0 = xr[lh * 2], a1 = xr[lh * 2 + 1];
        float4 a2 = xr[8 + lh * 2], a3 = xr[8 + lh * 2 + 1];
        bf16x8v af[2];
        af[0][0] = (short)f2bf(a0.x); af[0][1] = (short)f2bf(a0.y);
        af[0][2] = (short)f2bf(a0.z); af[0][3] = (short)f2bf(a0.w);
        af[0][4] = (short)f2bf(a1.x); af[0][5] = (short)f2bf(a1.y);
        af[0][6] = (short)f2bf(a1.z); af[0][7] = (short)f2bf(a1.w);
        af[1][0] = (short)f2bf(a2.x); af[1][1] = (short)f2bf(a2.y);
        af[1][2] = (short)f2bf(a2.z); af[1][3] = (short)f2bf(a2.w);
        af[1][4] = (short)f2bf(a3.x); af[1][5] = (short)f2bf(a3.y);
        af[1][6] = (short)f2bf(a3.z); af[1][7] = (short)f2bf(a3.w);

        if (wave < 2) {
            // ---- Q/K: swapped operands -> D row = f-in-block (4*lh+r), col = s (lr)
            __hip_bfloat16* dst = (wave == 0) ? qp : kp;
            const float scl = (wave == 0) ? QSCALE : 1.0f;
#pragma unroll
            for (int cb = 0; cb < 4; ++cb) {
                f32x4v acc = {0.f, 0.f, 0.f, 0.f};
                acc = __builtin_amdgcn_mfma_f32_16x16x32_bf16(wf[cb][0], af[0], acc, 0, 0, 0);
                acc = __builtin_amdgcn_mfma_f32_16x16x32_bf16(wf[cb][1], af[1], acc, 0, 0, 0);
                ushort4 o;
                o.x = f2bf((acc[0] + bias4[cb].x) * scl);
                o.y = f2bf((acc[1] + bias4[cb].y) * scl);
                o.z = f2bf((acc[2] + bias4[cb].z) * scl);
                o.w = f2bf((acc[3] + bias4[cb].w) * scl);
                // dst[((b,h,s = sbase+lr)]*64 + cb*16 + 4*lh .. +3]
                *reinterpret_cast<ushort4*>(
                    (unsigned short*)dst +
                    (((size_t)b * H_ + h) * S_ + sbase + lr) * E_ + cb * 16 + 4 * lh) = o;
            }
        } else {
            // ---- V: original orientation -> D row = s-in-tile (4*lh+r), col = f (lr)
#pragma unroll
            for (int cb = 0; cb < 4; ++cb) {
                f32x4v acc = {0.f, 0.f, 0.f, 0.f};
                acc = __builtin_amdgcn_mfma_f32_16x16x32_bf16(af[0], wf[cb][0], acc, 0, 0, 0);
                acc = __builtin_amdgcn_mfma_f32_16x16x32_bf16(af[1], wf[cb][1], acc, 0, 0, 0);
                float bv4 = bvals[cb];
                ushort4 o;
                o.x = f2bf(acc[0] + bv4);
                o.y = f2bf(acc[1] + bv4);
                o.z = f2bf(acc[2] + bv4);
                o.w = f2bf(acc[3] + bv4);
                // vtp[((b,h,f = cb*16+lr)]*S + sbase + 4*lh .. +3]
                *reinterpret_cast<ushort4*>(
                    (unsigned short*)vtp +
                    (((size_t)b * H_ + h) * E_ + cb * 16 + lr) * S_ + sbase + 4 * lh) = o;
            }
        }
    }
}

// ---------------------------------------------------------------------------
// Flash attention (unchanged from R8): global_load_lds dbuf staging, coalesced
// bit-packed mask, raw exp2 softmax with deferred denominator reduction.
// grid = B*H * S/(QB*NW) = 1024, block = 256
// ---------------------------------------------------------------------------
__global__ __launch_bounds__(256, 4)
void attn_kernel(const __hip_bfloat16* __restrict__ qp,
                 const __hip_bfloat16* __restrict__ kp,
                 const __hip_bfloat16* __restrict__ vtp,
                 const int* __restrict__ mask,
                 float* __restrict__ out)
{
    __shared__ unsigned short Kt[2][KT * E_];    // swizzled [k][e], dbuf
    __shared__ unsigned short Vs[2][KT * E_];    // swizzled [e][k], dbuf
    __shared__ unsigned short Pt[NW][16 * KT];   // swizzled [q][k], per wave

    const int tid  = threadIdx.x;
    const int wave = tid >> 6;
    const int lane = tid & 63;
    const int lr   = lane & 15;
    const int lh   = lane >> 4;
    const int nqt  = S_ / (QB * NW);
    const int bh   = blockIdx.x / nqt;
    const int qt   = blockIdx.x % nqt;
    const int qbase = qt * (QB * NW) + wave * QB;

    const __hip_bfloat16* qrow = qp + ((size_t)bh * S_ + qbase + lr) * E_;
    bf16x8v aq0 = *reinterpret_cast<const bf16x8v*>(qrow + lh * 8);
    bf16x8v aq1 = *reinterpret_cast<const bf16x8v*>(qrow + lh * 8 + 32);

    float psum[4];          // per-lane partial softmax denominators
    f32x4v Oa[4];
#pragma unroll
    for (int r = 0; r < 4; ++r) psum[r] = 0.f;
#pragma unroll
    for (int eb = 0; eb < 4; ++eb) Oa[eb] = {0.f, 0.f, 0.f, 0.f};

    const char* kgb = (const char*)(kp  + (size_t)bh * S_ * E_);
    const char* vgb = (const char*)(vtp + (size_t)bh * E_ * S_);
    // coalesced mask base: lane covers row lr, 16B chunk lh (of 4 per 64B seg)
    const char* mwb = (const char*)mask +
        (((size_t)bh * S_ + qbase + lr) * S_) * 4 + lh * 16;

    // K/V staging geometry: wave w stages rows [w*16, w*16+16); linear LDS
    // dest, source column pre-XOR'd to match the read-side swizzle
    const int rowA = wave * 16 + (lane >> 3);
    const int rowB = rowA + 8;
    const int e2   = (((lane & 7) ^ (lane >> 3)) << 4);
    const size_t koffA = (size_t)rowA * 128 + e2;        // + kb*128
    const size_t koffB = (size_t)rowB * 128 + e2;
    const size_t voffA = (size_t)rowA * (S_ * 2) + e2;   // + kb*2
    const size_t voffB = (size_t)rowB * (S_ * 2) + e2;

    char* Kt0 = (char*)(Kt[0]); char* Kt1 = (char*)(Kt[1]);
    char* Vs0 = (char*)(Vs[0]); char* Vs1 = (char*)(Vs[1]);
    char* PtB = (char*)(Pt[wave]);

    int4 mr0, mr1, mr2, mr3;   // coalesced raw mask regs (tile t)

    // ---- prologue: stage tile 0 into buf0; load mask tile 0 (coalesced)
    gl_lds16(kgb + koffA, Kt0 + wave * 2048);
    gl_lds16(kgb + koffB, Kt0 + wave * 2048 + 1024);
    gl_lds16(vgb + voffA, Vs0 + wave * 2048);
    gl_lds16(vgb + voffB, Vs0 + wave * 2048 + 1024);
    mr0 = *reinterpret_cast<const int4*>(mwb);
    mr1 = *reinterpret_cast<const int4*>(mwb + 64);
    mr2 = *reinterpret_cast<const int4*>(mwb + 128);
    mr3 = *reinterpret_cast<const int4*>(mwb + 192);
    __syncthreads();

    for (int kt = 0; kt < NT; ++kt) {
        const int kb  = kt * KT;
        char* KtC = (kt & 1) ? Kt1 : Kt0;
        char* VsC = (kt & 1) ? Vs1 : Vs0;
        char* KtN = (kt & 1) ? Kt0 : Kt1;
        char* VsN = (kt & 1) ? Vs0 : Vs1;
        const bool pref = (kt + 1 < NT);

        // ---- issue next tile's K/V staging (async DMA, cannot be sunk)
        if (pref) {
            const size_t kadd = (size_t)(kb + KT) * 128;
            const size_t vadd = (size_t)(kb + KT) * 2;
            gl_lds16(kgb + kadd + koffA, KtN + wave * 2048);
            gl_lds16(kgb + kadd + koffB, KtN + wave * 2048 + 1024);
            gl_lds16(vgb + vadd + voffA, VsN + wave * 2048);
            gl_lds16(vgb + vadd + voffB, VsN + wave * 2048 + 1024);
        }

        // ---- pack THIS tile's mask (regs loaded last iter, long resolved):
        // bit p of wm = mask int p of row lr;   p = lh*4 + i*16 + j
        unsigned long long wm;
        {
            unsigned n0 = (mr0.x & 1) | ((mr0.y & 1) << 1) | ((mr0.z & 1) << 2) | ((mr0.w & 1) << 3);
            unsigned n1 = (mr1.x & 1) | ((mr1.y & 1) << 1) | ((mr1.z & 1) << 2) | ((mr1.w & 1) << 3);
            unsigned n2 = (mr2.x & 1) | ((mr2.y & 1) << 1) | ((mr2.z & 1) << 2) | ((mr2.w & 1) << 3);
            unsigned n3 = (mr3.x & 1) | ((mr3.y & 1) << 1) | ((mr3.z & 1) << 2) | ((mr3.w & 1) << 3);
            int sh = lh * 4;
            wm = ((unsigned long long)n0 << sh) |
                 ((unsigned long long)n1 << (sh + 16)) |
                 ((unsigned long long)n2 << (sh + 32)) |
                 ((unsigned long long)n3 << (sh + 48));
            wm |= __shfl_xor(wm, 16);
            wm |= __shfl_xor(wm, 32);   // all 4 lanes of row lr now hold word
        }

        // ---- issue next tile's coalesced mask loads
        if (pref) {
            const char* mp = mwb + (size_t)(kb + KT) * 4;
            mr0 = *reinterpret_cast<const int4*>(mp);
            mr1 = *reinterpret_cast<const int4*>(mp + 64);
            mr2 = *reinterpret_cast<const int4*>(mp + 128);
            mr3 = *reinterpret_cast<const int4*>(mp + 192);
        }

        // ---- QK^T : D layout row = 4*lh+r (q), col = lr (k within cb)
        f32x4v sc[4];
#pragma unroll
        for (int cb = 0; cb < 4; ++cb) {
            int kcol = cb * 16 + lr;
            bf16x8v bk0 = *reinterpret_cast<bf16x8v*>(
                KtC + ((kcol * 128 + lh * 16) ^ ((kcol & 7) << 4)));
            bf16x8v bk1 = *reinterpret_cast<bf16x8v*>(
                KtC + ((kcol * 128 + 64 + lh * 16) ^ ((kcol & 7) << 4)));
            f32x4v a = {0.f, 0.f, 0.f, 0.f};
            a = __builtin_amdgcn_mfma_f32_16x16x32_bf16(aq0, bk0, a, 0, 0, 0);
            a = __builtin_amdgcn_mfma_f32_16x16x32_bf16(aq1, bk1, a, 0, 0, 0);
            sc[cb] = a;
        }

        // ---- P = exp2(sc) raw (|sc| <~ 8 << 127 overflow); per-lane partial
        // denominators; write P (bf16) to per-wave swizzled LDS tile.
#pragma unroll
        for (int r = 0; r < 4; ++r) {
            int q = 4 * lh + r;
            float rs = 0.f;
#pragma unroll
            for (int cb = 0; cb < 4; ++cb) {
                float pv = __builtin_amdgcn_exp2f(sc[cb][r]);
                rs += pv;
                *reinterpret_cast<unsigned short*>(
                    PtB + ((q * 128 + (cb * 16 + lr) * 2) ^ ((q & 7) << 4))) = f2bf(pv);
            }
            psum[r] += rs;
        }

        // ---- PV, dropout via bit-test on the row word (k = mh*32 + lh*8 + j)
#pragma unroll
        for (int mh = 0; mh < 2; ++mh) {
            int k0 = mh * 32 + lh * 8;
            bf16x8v pa = *reinterpret_cast<bf16x8v*>(
                PtB + ((lr * 128 + k0 * 2) ^ ((lr & 7) << 4)));
            unsigned mby = (unsigned)(wm >> ((mh * 4 + lh) * 8)) & 0xffu;
#pragma unroll
            for (int j = 0; j < 8; ++j)
                pa[j] = (mby & (1u << j)) ? pa[j] : (short)0;
#pragma unroll
            for (int eb = 0; eb < 4; ++eb) {
                int e = eb * 16 + lr;
                bf16x8v vb = *reinterpret_cast<bf16x8v*>(
                    VsC + ((e * 128 + k0 * 2) ^ ((e & 7) << 4)));
                Oa[eb] = __builtin_amdgcn_mfma_f32_16x16x32_bf16(pa, vb, Oa[eb], 0, 0, 0);
            }
        }

        __syncthreads();   // drains: next tile's staging landed, bufs safe
    }

    // ---- epilogue: reduce denominators once; out = O * (1/0.9) / lsum
    constexpr float KEEP_INV = 1.0f / 0.9f;
    float* orow = out + ((size_t)bh * S_ + qbase) * E_;
#pragma unroll
    for (int r = 0; r < 4; ++r) {
        float s = psum[r];
#pragma unroll
        for (int off = 1; off < 16; off <<= 1)
            s += __shfl_xor(s, off);
        float inv = KEEP_INV / s;
        int q = 4 * lh + r;
#pragma unroll
        for (int eb = 0; eb < 4; ++eb)
            orow[(size_t)q * E_ + eb * 16 + lr] = Oa[eb][r] * inv;
    }
}

extern "C" void kernel_launch(void* const* d_in, const int* in_sizes, int n_in,
                              void* d_out, int out_size, void* d_ws, size_t ws_size,
                              hipStream_t stream) {
    (void)in_sizes; (void)n_in; (void)out_size; (void)ws_size;
    const float* query = (const float*)d_in[0];
    const float* key   = (const float*)d_in[1];
    const float* value = (const float*)d_in[2];
    const float* Wq    = (const float*)d_in[3];
    const float* bq    = (const float*)d_in[4];
    const float* Wk    = (const float*)d_in[5];
    const float* bk    = (const float*)d_in[6];
    const float* Wv    = (const float*)d_in[7];
    const float* bv    = (const float*)d_in[8];
    const int*   mask  = (const int*)d_in[9];
    float*       out   = (float*)d_out;

    const size_t per = (size_t)B_ * H_ * S_ * E_;
    __hip_bfloat16* qp  = (__hip_bfloat16*)d_ws;
    __hip_bfloat16* kp  = qp + per;
    __hip_bfloat16* vtp = kp + per;

    proj_kernel<<<B_ * (S_ / 16) * HSPLIT, 192, 0, stream>>>(query, key, value,
                                                             Wq, bq, Wk, bk, Wv, bv,
                                                             qp, kp, vtp);
    attn_kernel<<<B_ * H_ * (S_ / (QB * NW)), 256, 0, stream>>>(qp, kp, vtp, mask, out);
}

// Round 10
// 169.557 us; speedup vs baseline: 1.0218x; 1.0218x over previous
//
#include <hip/hip_runtime.h>
#include <hip/hip_bf16.h>

#define B_ 4
#define S_ 2048
#define H_ 8
#define E_ 64
#define NW 4      // waves per attention block
#define QB 16     // q rows per wave
#define KT 64     // k/v tile size
#define NT (S_ / KT)
#define HSPLIT 4  // proj: head-groups per s-tile (2 heads per block)

typedef __attribute__((ext_vector_type(8))) short bf16x8v;
typedef __attribute__((ext_vector_type(4))) float f32x4v;

static __device__ __forceinline__ unsigned short f2bf(float f) {
    __hip_bfloat16 h = __float2bfloat16(f);
    return *reinterpret_cast<unsigned short*>(&h);
}

// async global->LDS DMA, 16B/lane
static __device__ __forceinline__ void gl_lds16(const void* g, void* lds) {
    __builtin_amdgcn_global_load_lds(
        (const __attribute__((address_space(1))) unsigned int*)g,
        (__attribute__((address_space(3))) unsigned int*)lds, 16, 0, 0);
}

// ---------------------------------------------------------------------------
// Projection (R9, at HBM-BW floor ~40us): q scaled into exp2 domain, K plain,
// V pre-transposed. grid = B * S/16 * HSPLIT, block = 192.
// ---------------------------------------------------------------------------
__global__ __launch_bounds__(192)
void proj_kernel(const float* __restrict__ query, const float* __restrict__ key,
                 const float* __restrict__ value,
                 const float* __restrict__ Wq, const float* __restrict__ bq,
                 const float* __restrict__ Wk, const float* __restrict__ bk,
                 const float* __restrict__ Wv, const float* __restrict__ bv,
                 __hip_bfloat16* __restrict__ qp, __hip_bfloat16* __restrict__ kp,
                 __hip_bfloat16* __restrict__ vtp)
{
    const int tid  = threadIdx.x;
    const int wave = tid >> 6;
    const int lane = tid & 63;
    const int lr   = lane & 15;
    const int lh   = lane >> 4;
    const int ntile = S_ / 16;
    const int hb    = blockIdx.x % HSPLIT;
    const int sbase = ((blockIdx.x / HSPLIT) % ntile) * 16;
    const int b     = blockIdx.x / (ntile * HSPLIT);

    const float* x    = (wave == 0) ? query : (wave == 1) ? key : value;
    const float* W    = (wave == 0) ? Wq    : (wave == 1) ? Wk  : Wv;
    const float* bias = (wave == 0) ? bq    : (wave == 1) ? bk  : bv;

    bf16x8v wf[4][2];
#pragma unroll
    for (int cb = 0; cb < 4; ++cb)
#pragma unroll
        for (int hf = 0; hf < 2; ++hf)
#pragma unroll
            for (int j = 0; j < 8; ++j) {
                int e = lh * 8 + j + 32 * hf;
                wf[cb][hf][j] = (short)f2bf(W[e * E_ + cb * 16 + lr]);
            }

    float4 bias4[4];
    float  bvals[4];
#pragma unroll
    for (int cb = 0; cb < 4; ++cb) {
        bias4[cb] = *reinterpret_cast<const float4*>(bias + cb * 16 + 4 * lh);
        bvals[cb] = bias[cb * 16 + lr];
    }

    const float QSCALE = 0.18033688011112042f;   // log2e / 8

#pragma unroll
    for (int hi = 0; hi < H_ / HSPLIT; ++hi) {
        const int h = hb * (H_ / HSPLIT) + hi;
        const float* xrow = x + (((size_t)b * S_ + sbase + lr) * H_ + h) * E_;
        const float4* xr = reinterpret_cast<const float4*>(xrow);
        float4 a0 = xr[lh * 2], a1 = xr[lh * 2 + 1];
        float4 a2 = xr[8 + lh * 2], a3 = xr[8 + lh * 2 + 1];
        bf16x8v af[2];
        af[0][0] = (short)f2bf(a0.x); af[0][1] = (short)f2bf(a0.y);
        af[0][2] = (short)f2bf(a0.z); af[0][3] = (short)f2bf(a0.w);
        af[0][4] = (short)f2bf(a1.x); af[0][5] = (short)f2bf(a1.y);
        af[0][6] = (short)f2bf(a1.z); af[0][7] = (short)f2bf(a1.w);
        af[1][0] = (short)f2bf(a2.x); af[1][1] = (short)f2bf(a2.y);
        af[1][2] = (short)f2bf(a2.z); af[1][3] = (short)f2bf(a2.w);
        af[1][4] = (short)f2bf(a3.x); af[1][5] = (short)f2bf(a3.y);
        af[1][6] = (short)f2bf(a3.z); af[1][7] = (short)f2bf(a3.w);

        if (wave < 2) {
            __hip_bfloat16* dst = (wave == 0) ? qp : kp;
            const float scl = (wave == 0) ? QSCALE : 1.0f;
#pragma unroll
            for (int cb = 0; cb < 4; ++cb) {
                f32x4v acc = {0.f, 0.f, 0.f, 0.f};
                acc = __builtin_amdgcn_mfma_f32_16x16x32_bf16(wf[cb][0], af[0], acc, 0, 0, 0);
                acc = __builtin_amdgcn_mfma_f32_16x16x32_bf16(wf[cb][1], af[1], acc, 0, 0, 0);
                ushort4 o;
                o.x = f2bf((acc[0] + bias4[cb].x) * scl);
                o.y = f2bf((acc[1] + bias4[cb].y) * scl);
                o.z = f2bf((acc[2] + bias4[cb].z) * scl);
                o.w = f2bf((acc[3] + bias4[cb].w) * scl);
                *reinterpret_cast<ushort4*>(
                    (unsigned short*)dst +
                    (((size_t)b * H_ + h) * S_ + sbase + lr) * E_ + cb * 16 + 4 * lh) = o;
            }
        } else {
#pragma unroll
            for (int cb = 0; cb < 4; ++cb) {
                f32x4v acc = {0.f, 0.f, 0.f, 0.f};
                acc = __builtin_amdgcn_mfma_f32_16x16x32_bf16(af[0], wf[cb][0], acc, 0, 0, 0);
                acc = __builtin_amdgcn_mfma_f32_16x16x32_bf16(af[1], wf[cb][1], acc, 0, 0, 0);
                float bv4 = bvals[cb];
                ushort4 o;
                o.x = f2bf(acc[0] + bv4);
                o.y = f2bf(acc[1] + bv4);
                o.z = f2bf(acc[2] + bv4);
                o.w = f2bf(acc[3] + bv4);
                *reinterpret_cast<ushort4*>(
                    (unsigned short*)vtp +
                    (((size_t)b * H_ + h) * E_ + cb * 16 + lr) * S_ + sbase + 4 * lh) = o;
            }
        }
    }
}

// ---------------------------------------------------------------------------
// Flash attention = R8 body + counted-vmcnt tile boundary:
//   - 4x global_load_lds (staging, pinned oldest by sched_barrier fences)
//   - 4x coalesced int4 mask loads (compiler-tracked, stay in flight
//     across the barrier; compiler's own counted wait resolves them at
//     next tile's pack)
//   - boundary: s_waitcnt vmcnt(4) + raw s_barrier  (NO full drain)
// grid = B*H * S/(QB*NW) = 1024, block = 256
// ---------------------------------------------------------------------------
__global__ __launch_bounds__(256, 4)
void attn_kernel(const __hip_bfloat16* __restrict__ qp,
                 const __hip_bfloat16* __restrict__ kp,
                 const __hip_bfloat16* __restrict__ vtp,
                 const int* __restrict__ mask,
                 float* __restrict__ out)
{
    __shared__ unsigned short Kt[2][KT * E_];    // swizzled [k][e], dbuf
    __shared__ unsigned short Vs[2][KT * E_];    // swizzled [e][k], dbuf
    __shared__ unsigned short Pt[NW][16 * KT];   // swizzled [q][k], per wave

    const int tid  = threadIdx.x;
    const int wave = tid >> 6;
    const int lane = tid & 63;
    const int lr   = lane & 15;
    const int lh   = lane >> 4;
    const int nqt  = S_ / (QB * NW);
    const int bh   = blockIdx.x / nqt;
    const int qt   = blockIdx.x % nqt;
    const int qbase = qt * (QB * NW) + wave * QB;

    const __hip_bfloat16* qrow = qp + ((size_t)bh * S_ + qbase + lr) * E_;
    bf16x8v aq0 = *reinterpret_cast<const bf16x8v*>(qrow + lh * 8);
    bf16x8v aq1 = *reinterpret_cast<const bf16x8v*>(qrow + lh * 8 + 32);

    float psum[4];
    f32x4v Oa[4];
#pragma unroll
    for (int r = 0; r < 4; ++r) psum[r] = 0.f;
#pragma unroll
    for (int eb = 0; eb < 4; ++eb) Oa[eb] = {0.f, 0.f, 0.f, 0.f};

    const char* kgb = (const char*)(kp  + (size_t)bh * S_ * E_);
    const char* vgb = (const char*)(vtp + (size_t)bh * E_ * S_);
    const char* mwb = (const char*)mask +
        (((size_t)bh * S_ + qbase + lr) * S_) * 4 + lh * 16;

    const int rowA = wave * 16 + (lane >> 3);
    const int rowB = rowA + 8;
    const int e2   = (((lane & 7) ^ (lane >> 3)) << 4);
    const size_t koffA = (size_t)rowA * 128 + e2;
    const size_t koffB = (size_t)rowB * 128 + e2;
    const size_t voffA = (size_t)rowA * (S_ * 2) + e2;
    const size_t voffB = (size_t)rowB * (S_ * 2) + e2;

    char* Kt0 = (char*)(Kt[0]); char* Kt1 = (char*)(Kt[1]);
    char* Vs0 = (char*)(Vs[0]); char* Vs1 = (char*)(Vs[1]);
    char* PtB = (char*)(Pt[wave]);

    int4 mr0, mr1, mr2, mr3;

    // ---- prologue: stage tile 0 (oldest 4 vmem); mask tile 0 after fence
    gl_lds16(kgb + koffA, Kt0 + wave * 2048);
    gl_lds16(kgb + koffB, Kt0 + wave * 2048 + 1024);
    gl_lds16(vgb + voffA, Vs0 + wave * 2048);
    gl_lds16(vgb + voffB, Vs0 + wave * 2048 + 1024);
    __builtin_amdgcn_sched_barrier(0);
    mr0 = *reinterpret_cast<const int4*>(mwb);
    mr1 = *reinterpret_cast<const int4*>(mwb + 64);
    mr2 = *reinterpret_cast<const int4*>(mwb + 128);
    mr3 = *reinterpret_cast<const int4*>(mwb + 192);
    __builtin_amdgcn_sched_barrier(0);
    asm volatile("s_waitcnt vmcnt(4)" ::: "memory");
    __builtin_amdgcn_s_barrier();
    __builtin_amdgcn_sched_barrier(0);

    for (int kt = 0; kt < NT; ++kt) {
        const int kb  = kt * KT;
        char* KtC = (kt & 1) ? Kt1 : Kt0;
        char* VsC = (kt & 1) ? Vs1 : Vs0;
        char* KtN = (kt & 1) ? Kt0 : Kt1;
        char* VsN = (kt & 1) ? Vs0 : Vs1;
        const bool pref = (kt + 1 < NT);

        // ---- issue next tile's K/V staging FIRST (must stay oldest 4 vmem)
        if (pref) {
            const size_t kadd = (size_t)(kb + KT) * 128;
            const size_t vadd = (size_t)(kb + KT) * 2;
            gl_lds16(kgb + kadd + koffA, KtN + wave * 2048);
            gl_lds16(kgb + kadd + koffB, KtN + wave * 2048 + 1024);
            gl_lds16(vgb + vadd + voffA, VsN + wave * 2048);
            gl_lds16(vgb + vadd + voffB, VsN + wave * 2048 + 1024);
        }
        __builtin_amdgcn_sched_barrier(0);

        // ---- pack THIS tile's mask (regs loaded one tile ago)
        unsigned long long wm;
        {
            unsigned n0 = (mr0.x & 1) | ((mr0.y & 1) << 1) | ((mr0.z & 1) << 2) | ((mr0.w & 1) << 3);
            unsigned n1 = (mr1.x & 1) | ((mr1.y & 1) << 1) | ((mr1.z & 1) << 2) | ((mr1.w & 1) << 3);
            unsigned n2 = (mr2.x & 1) | ((mr2.y & 1) << 1) | ((mr2.z & 1) << 2) | ((mr2.w & 1) << 3);
            unsigned n3 = (mr3.x & 1) | ((mr3.y & 1) << 1) | ((mr3.z & 1) << 2) | ((mr3.w & 1) << 3);
            int sh = lh * 4;
            wm = ((unsigned long long)n0 << sh) |
                 ((unsigned long long)n1 << (sh + 16)) |
                 ((unsigned long long)n2 << (sh + 32)) |
                 ((unsigned long long)n3 << (sh + 48));
            wm |= __shfl_xor(wm, 16);
            wm |= __shfl_xor(wm, 32);
        }

        // ---- issue next tile's coalesced mask loads (newer than staging)
        if (pref) {
            const char* mp = mwb + (size_t)(kb + KT) * 4;
            mr0 = *reinterpret_cast<const int4*>(mp);
            mr1 = *reinterpret_cast<const int4*>(mp + 64);
            mr2 = *reinterpret_cast<const int4*>(mp + 128);
            mr3 = *reinterpret_cast<const int4*>(mp + 192);
        }
        __builtin_amdgcn_sched_barrier(0);

        // ---- QK^T : D layout row = 4*lh+r (q), col = lr (k within cb)
        f32x4v sc[4];
#pragma unroll
        for (int cb = 0; cb < 4; ++cb) {
            int kcol = cb * 16 + lr;
            bf16x8v bk0 = *reinterpret_cast<bf16x8v*>(
                KtC + ((kcol * 128 + lh * 16) ^ ((kcol & 7) << 4)));
            bf16x8v bk1 = *reinterpret_cast<bf16x8v*>(
                KtC + ((kcol * 128 + 64 + lh * 16) ^ ((kcol & 7) << 4)));
            f32x4v a = {0.f, 0.f, 0.f, 0.f};
            a = __builtin_amdgcn_mfma_f32_16x16x32_bf16(aq0, bk0, a, 0, 0, 0);
            a = __builtin_amdgcn_mfma_f32_16x16x32_bf16(aq1, bk1, a, 0, 0, 0);
            sc[cb] = a;
        }

        // ---- P = exp2(sc) raw; per-lane partial denominators; P -> LDS
#pragma unroll
        for (int r = 0; r < 4; ++r) {
            int q = 4 * lh + r;
            float rs = 0.f;
#pragma unroll
            for (int cb = 0; cb < 4; ++cb) {
                float pv = __builtin_amdgcn_exp2f(sc[cb][r]);
                rs += pv;
                *reinterpret_cast<unsigned short*>(
                    PtB + ((q * 128 + (cb * 16 + lr) * 2) ^ ((q & 7) << 4))) = f2bf(pv);
            }
            psum[r] += rs;
        }

        // ---- PV, dropout via bit-test on the row word
#pragma unroll
        for (int mh = 0; mh < 2; ++mh) {
            int k0 = mh * 32 + lh * 8;
            bf16x8v pa = *reinterpret_cast<bf16x8v*>(
                PtB + ((lr * 128 + k0 * 2) ^ ((lr & 7) << 4)));
            unsigned mby = (unsigned)(wm >> ((mh * 4 + lh) * 8)) & 0xffu;
#pragma unroll
            for (int j = 0; j < 8; ++j)
                pa[j] = (mby & (1u << j)) ? pa[j] : (short)0;
#pragma unroll
            for (int eb = 0; eb < 4; ++eb) {
                int e = eb * 16 + lr;
                bf16x8v vb = *reinterpret_cast<bf16x8v*>(
                    VsC + ((e * 128 + k0 * 2) ^ ((e & 7) << 4)));
                Oa[eb] = __builtin_amdgcn_mfma_f32_16x16x32_bf16(pa, vb, Oa[eb], 0, 0, 0);
            }
        }

        // ---- counted tile boundary: staging (oldest 4) landed; mask loads
        // (4 newer) stay in flight across the barrier.
        if (pref) {
            asm volatile("s_waitcnt vmcnt(4)" ::: "memory");
        } else {
            asm volatile("s_waitcnt vmcnt(0)" ::: "memory");
        }
        __builtin_amdgcn_s_barrier();
        __builtin_amdgcn_sched_barrier(0);
    }

    // ---- epilogue: reduce denominators once; out = O * (1/0.9) / lsum
    constexpr float KEEP_INV = 1.0f / 0.9f;
    float* orow = out + ((size_t)bh * S_ + qbase) * E_;
#pragma unroll
    for (int r = 0; r < 4; ++r) {
        float s = psum[r];
#pragma unroll
        for (int off = 1; off < 16; off <<= 1)
            s += __shfl_xor(s, off);
        float inv = KEEP_INV / s;
        int q = 4 * lh + r;
#pragma unroll
        for (int eb = 0; eb < 4; ++eb)
            orow[(size_t)q * E_ + eb * 16 + lr] = Oa[eb][r] * inv;
    }
}

extern "C" void kernel_launch(void* const* d_in, const int* in_sizes, int n_in,
                              void* d_out, int out_size, void* d_ws, size_t ws_size,
                              hipStream_t stream) {
    (void)in_sizes; (void)n_in; (void)out_size; (void)ws_size;
    const float* query = (const float*)d_in[0];
    const float* key   = (const float*)d_in[1];
    const float* value = (const float*)d_in[2];
    const float* Wq    = (const float*)d_in[3];
    const float* bq    = (const float*)d_in[4];
    const float* Wk    = (const float*)d_in[5];
    const float* bk    = (const float*)d_in[6];
    const float* Wv    = (const float*)d_in[7];
    const float* bv    = (const float*)d_in[8];
    const int*   mask  = (const int*)d_in[9];
    float*       out   = (float*)d_out;

    const size_t per = (size_t)B_ * H_ * S_ * E_;
    __hip_bfloat16* qp  = (__hip_bfloat16*)d_ws;
    __hip_bfloat16* kp  = qp + per;
    __hip_bfloat16* vtp = kp + per;

    proj_kernel<<<B_ * (S_ / 16) * HSPLIT, 192, 0, stream>>>(query, key, value,
                                                             Wq, bq, Wk, bk, Wv, bv,
                                                             qp, kp, vtp);
    attn_kernel<<<B_ * H_ * (S_ / (QB * NW)), 256, 0, stream>>>(qp, kp, vtp, mask, out);
}